// Round 9
// baseline (186.288 us; speedup 1.0000x reference)
//
#include <hip/hip_runtime.h>
#include <stdint.h>

#define BB    2048
#define DIN   4096
#define DOUT  4096

// ---------------------------------------------------------------------------
// i8 MFMA bit-GEMM. x,m -> ±1 int8; dot± = 2*sums - 4096;
// out = sums > thr  <=>  dot± > 2*thr - 4096. Exact in i32. (R7: absmax 0)
// ws: x8 ±1 [BB][DIN] @0 (8 MB); m8T ±1 [DOUT][DIN] @8MB (16 MB).
//
// R8 post-mortem (48us): LDS pipe = 70% of runtime (frag reads 27us @16cyc
// incl structural 4-way conflict + staging writes 6.8us); MFMA 15.6us.
// Frag-read count = MFMAs*(T+U)/(T*U) -> R9 goes T=2,U=4 (0.75x reads) via
// 256x128 block tile, 4 waves of 64m x 128n, BK=128 dbuf (96 KB LDS,
// 1 block/CU, 256 blocks = zero tail). Staging drops 512->384 MB.
// launch_bounds(256,1) lifts the 128-VGPR self-cap (R4); ks unroll 2 keeps
// live temps bounded (R5). Spill canary: WRITE_SIZE > 32.8 MB.
// ---------------------------------------------------------------------------

using v4i  = __attribute__((ext_vector_type(4)))  int;
using v16i = __attribute__((ext_vector_type(16))) int;

__device__ __forceinline__ void async_load16(const void* g, void* l) {
    __builtin_amdgcn_global_load_lds(
        (const __attribute__((address_space(1))) unsigned int*)g,
        (__attribute__((address_space(3))) unsigned int*)l,
        16, 0, 0);
}

// bytes {0,1} -> {+1, -1(0xFF)}; no cross-byte carries.
__device__ __forceinline__ unsigned int to_pm1(unsigned int c) {
    return c + ((c ^ 0x01010101u) * 255u);
}

// Fused packing (verified R7).
// blocks [0,BB): x int32 {0,1} row -> x8 ±1 bytes (same layout).
// blocks [BB, BB+4096): 64x64 transpose tile of masks -> m8T ±1 bytes.
__global__ void pack_all(const int* __restrict__ x,
                         const void* __restrict__ mraw,
                         char* __restrict__ x8,
                         char* __restrict__ m8T) {
    const int tid = threadIdx.x;
    if (blockIdx.x < BB) {
        const int row = blockIdx.x;
        const int4* src = (const int4*)(x + (size_t)row * DIN);
        unsigned int* dst = (unsigned int*)(x8 + (size_t)row * DIN);
        #pragma unroll
        for (int q = 0; q < 4; ++q) {
            int4 v = src[q * 256 + tid];           // coalesced 16B/lane
            unsigned int t = (unsigned int)(v.x & 1) |
                             ((unsigned int)(v.y & 1) << 8) |
                             ((unsigned int)(v.z & 1) << 16) |
                             ((unsigned int)(v.w & 1) << 24);
            dst[q * 256 + tid] = to_pm1(t);        // coalesced 4B/lane
        }
    } else {
        const int bw = blockIdx.x - BB;            // 0..4095
        const int k0 = (bw & 63) * 64;
        const int n0 = (bw >> 6) * 64;

        // inline dtype detect (u8-bool vs int32): wave-reduce 1 KB prefix.
        const unsigned char* mb = (const unsigned char*)mraw;
        int myv = (mb[tid] != 0) + (mb[tid + 256] != 0) +
                  (mb[tid + 512] != 0) + (mb[tid + 768] != 0);
        #pragma unroll
        for (int d = 32; d; d >>= 1) myv += __shfl_xor(myv, d);
        const bool isU8 = (myv > 64);   // u8 ~128/wave, int32 ~32/wave

        // 4x4 byte micro-tile per thread: rows k0+k4..+3, cols n0+n4..+3
        const int n4 = (tid & 15) * 4;
        const int k4 = (tid >> 4) * 4;
        unsigned int a[4];
        if (isU8) {
            #pragma unroll
            for (int r = 0; r < 4; ++r)
                a[r] = *(const unsigned int*)(mb + (size_t)(k0 + k4 + r) * DOUT + n0 + n4);
        } else {
            const int4* m32 = (const int4*)mraw;
            #pragma unroll
            for (int r = 0; r < 4; ++r) {
                int4 v = m32[((size_t)(k0 + k4 + r) * DOUT + n0 + n4) >> 2];
                a[r] = (unsigned int)(v.x & 1) |
                       ((unsigned int)(v.y & 1) << 8) |
                       ((unsigned int)(v.z & 1) << 16) |
                       ((unsigned int)(v.w & 1) << 24);
            }
        }
        // 4x4 byte transpose via v_perm (sel 0-3 = src1/lo, 4-7 = src0/hi)
        unsigned int x0 = __builtin_amdgcn_perm(a[1], a[0], 0x05010400u);
        unsigned int x1 = __builtin_amdgcn_perm(a[3], a[2], 0x05010400u);
        unsigned int x2 = __builtin_amdgcn_perm(a[1], a[0], 0x07030602u);
        unsigned int x3 = __builtin_amdgcn_perm(a[3], a[2], 0x07030602u);
        unsigned int c0 = __builtin_amdgcn_perm(x1, x0, 0x05040100u);
        unsigned int c1 = __builtin_amdgcn_perm(x1, x0, 0x07060302u);
        unsigned int c2 = __builtin_amdgcn_perm(x3, x2, 0x05040100u);
        unsigned int c3 = __builtin_amdgcn_perm(x3, x2, 0x07060302u);
        *(unsigned int*)(m8T + (size_t)(n0 + n4 + 0) * DIN + k0 + k4) = to_pm1(c0);
        *(unsigned int*)(m8T + (size_t)(n0 + n4 + 1) * DIN + k0 + k4) = to_pm1(c1);
        *(unsigned int*)(m8T + (size_t)(n0 + n4 + 2) * DIN + k0 + k4) = to_pm1(c2);
        *(unsigned int*)(m8T + (size_t)(n0 + n4 + 3) * DIN + k0 + k4) = to_pm1(c3);
    }
}

// i8 MFMA GEMM: 256(m)x128(n) block tile, 4 waves, wave tile 64m x 128n
// (T=2 x U=4 of v_mfma_i32_32x32x32_i8). BK=128, double-buffered LDS
// (96 KB, 1 block/CU, 256 blocks), async global->LDS staging.
// LDS layout: [row][slot], slot = kgroup ^ (row&7), 8 kgroups x 16 B.
__global__ __launch_bounds__(256, 1)
void bgemm(const char* __restrict__ x8,
           const char* __restrict__ m8T,
           const int* __restrict__ thr,
           int* __restrict__ out) {
    // XCD swizzle: flat%8 = XCD; each XCD gets a 4m x 8n patch
    // (A 4 MB + B 4 MB concurrent working set per XCD L2).
    const int flat = blockIdx.y * 32 + blockIdx.x;   // 256 blocks
    const int xcd  = flat & 7;
    const int idx  = flat >> 3;                      // 0..31
    const int bm   = (xcd & 1) * 4 + (idx & 3);      // 0..7
    const int bn   = (xcd >> 1) * 8 + (idx >> 2);    // 0..31
    const int m0   = bm * 256;
    const int o0   = bn * 128;

    const int tid  = threadIdx.x;
    const int lane = tid & 63;
    const int wv   = tid >> 6;           // wave 0..3
    const int wm   = wv * 64;            // wave tile m origin (n origin = 0)
    const int l31  = lane & 31;
    const int lh   = lane >> 5;
    const int rsw  = l31 & 7;            // row&7 term for frag reads

    __shared__ __align__(16) char lA[2][256 * 128];  // 64 KB
    __shared__ __align__(16) char lB[2][128 * 128];  // 32 KB

    // stage chunk c -> buf. Per instr: 8 rows x 128 B contiguous LDS.
    // lane: row = r0 + l/8, slot s = l&7, global kgroup g = s ^ (row&7).
    auto stage = [&](int c, int buf) {
        const int k0 = c * 128;
        const int r8 = lane >> 3;
        const int s  = lane & 7;
        #pragma unroll
        for (int h = 0; h < 8; ++h) {            // lA: 64 rows per wave
            const int r0  = wv * 64 + h * 8;
            const int row = r0 + r8;
            const int g   = s ^ (row & 7);
            async_load16(x8 + (size_t)(m0 + row) * DIN + k0 + g * 16,
                         &lA[buf][r0 * 128 + lane * 16]);
        }
        #pragma unroll
        for (int h = 0; h < 4; ++h) {            // lB: 32 rows per wave
            const int r0  = wv * 32 + h * 8;
            const int row = r0 + r8;
            const int g   = s ^ (row & 7);
            async_load16(m8T + (size_t)(o0 + row) * DIN + k0 + g * 16,
                         &lB[buf][r0 * 128 + lane * 16]);
        }
    };

    v16i acc[2][4];
    #pragma unroll
    for (int t = 0; t < 2; ++t)
        #pragma unroll
        for (int u = 0; u < 4; ++u)
            acc[t][u] = (v16i)(0);

    stage(0, 0);
    __syncthreads();

    for (int c = 0; c < 32; ++c) {
        const int buf = c & 1;
        if (c < 31) stage(c + 1, buf ^ 1);   // async, overlaps compute

        #pragma unroll 2
        for (int ks = 0; ks < 4; ++ks) {
            const int slot = ((ks * 2 + lh) ^ rsw) * 16;
            v4i aF[2], bF[4];
            #pragma unroll
            for (int t = 0; t < 2; ++t)
                aF[t] = *(const v4i*)&lA[buf][(wm + t * 32 + l31) * 128 + slot];
            #pragma unroll
            for (int u = 0; u < 4; ++u)
                bF[u] = *(const v4i*)&lB[buf][(u * 32 + l31) * 128 + slot];
            #pragma unroll
            for (int t = 0; t < 2; ++t)
                #pragma unroll
                for (int u = 0; u < 4; ++u)
                    acc[t][u] = __builtin_amdgcn_mfma_i32_32x32x32_i8(
                        aF[t], bF[u], acc[t][u], 0, 0, 0);
        }
        __syncthreads();   // drains chunk+1 loads; releases buf
    }

    // epilogue: out = (dot± > 2*thr - 4096).
    // C/D layout (verified R7): col = lane&31; row = (reg&3)+8*(reg>>2)+4*(lane>>5).
    #pragma unroll
    for (int u = 0; u < 4; ++u) {
        const int o   = o0 + u * 32 + l31;
        const int lim = 2 * thr[o] - DIN;
        #pragma unroll
        for (int t = 0; t < 2; ++t) {
            #pragma unroll
            for (int r = 0; r < 16; ++r) {
                const int rowl = (r & 3) + 8 * (r >> 2) + 4 * lh;
                const int b    = m0 + wm + t * 32 + rowl;
                out[(size_t)b * DOUT + o] = (acc[t][u][r] > lim) ? 1 : 0;
            }
        }
    }
}

extern "C" void kernel_launch(void* const* d_in, const int* in_sizes, int n_in,
                              void* d_out, int out_size, void* d_ws, size_t ws_size,
                              hipStream_t stream) {
    const int* x          = (const int*)d_in[0];
    const void* masks     = d_in[1];           // bool: u8 or int32 (detected inline)
    const int* thresholds = (const int*)d_in[2];
    int* out              = (int*)d_out;

    char* x8  = (char*)d_ws;                          // 8 MB
    char* m8T = (char*)d_ws + ((size_t)8 << 20);      // 16 MB

    pack_all<<<BB + 4096, 256, 0, stream>>>(x, masks, x8, m8T);
    bgemm<<<dim3(32, 8), 256, 0, stream>>>(x8, m8T, thresholds, out);
}

// Round 11
// 177.910 us; speedup vs baseline: 1.0471x; 1.0471x over previous
//
#include <hip/hip_runtime.h>
#include <stdint.h>

#define BB    2048
#define DIN   4096
#define DOUT  4096

// ---------------------------------------------------------------------------
// i8 MFMA bit-GEMM (R7/R8-verified math). x,m -> ±1 int8; dot± = 2*sums-4096;
// out = sums > thr  <=>  dot± > 2*thr - 4096. Exact in i32.
//
// R10 lesson: fp4 e2m1 port failed correctness (suspect: fp4 operand reg
// placement / scale-block semantics — unobservable blind); reverted dtype,
// KEPT the K-major layout idea.
//
// K-major panel layout (NEW, the point of this round):
//   x8p : [256][2048][16B] @ 0      (8 MB)   panel p = k/16, row = b
//   b8p : [256][4096][16B] @ 8 MB  (16 MB)   panel p = k/16, row = o
// -> frag reads: 32 consecutive 16B addrs per lane-half = conflict-free
//    (R8: 4.19M conflicts = 4cyc/read structural to row-major+swizzle);
// -> global_load_lds stays contiguous 1 KB/instr; zero swizzle math.
//
// Shape: R8's proven occupancy point — 128x128 tile, T=U=2 of 32x32x32_i8,
// BK=128 (8 panels/chunk), dbuf LDS 64 KB, 512 blocks = 2/CU, XCD swizzle.
// Spill canary: WRITE_SIZE > 32.8 MB. R9 lesson: never drop below 2 bl/CU.
// ---------------------------------------------------------------------------

using v4i  = __attribute__((ext_vector_type(4)))  int;
using v16i = __attribute__((ext_vector_type(16))) int;

__device__ __forceinline__ void async_load16(const void* g, void* l) {
    __builtin_amdgcn_global_load_lds(
        (const __attribute__((address_space(1))) unsigned int*)g,
        (__attribute__((address_space(3))) unsigned int*)l,
        16, 0, 0);
}

// bytes {0,1} -> {+1, -1(0xFF)}; no cross-byte carries.
__device__ __forceinline__ unsigned int to_pm1(unsigned int c) {
    return c + ((c ^ 0x01010101u) * 255u);
}

// Fused packing.
// blocks [0,256): x -> x8p K-major. block = (row-tile 64) x (panel-tile 32);
//   lane = row, (wave,j) = panel -> 16-B stores are wave-coalesced (1 KB).
// blocks [256, 256+4096): 64x64 mask transpose tile (R7-verified v_perm)
//   -> b8p K-major, 4-B stores into 16-B panel groups.
__global__ void pack_all(const int* __restrict__ x,
                         const void* __restrict__ mraw,
                         char* __restrict__ x8p,
                         char* __restrict__ b8p) {
    const int tid = threadIdx.x;
    if (blockIdx.x < 256) {
        const int br  = blockIdx.x & 31;          // row tile (64 rows)
        const int bp  = blockIdx.x >> 5;          // panel tile (32 panels)
        const int row = br * 64 + (tid & 63);
        const int w   = tid >> 6;
        #pragma unroll
        for (int j = 0; j < 8; ++j) {
            const int p = bp * 32 + w * 8 + j;    // global panel, k=[16p,16p+16)
            const int4* src = (const int4*)(x + (size_t)row * DIN + p * 16);
            int4 a0 = src[0], a1 = src[1], a2 = src[2], a3 = src[3];
            uint4 v;
            v.x = to_pm1((unsigned)(a0.x & 1) | ((unsigned)(a0.y & 1) << 8) |
                         ((unsigned)(a0.z & 1) << 16) | ((unsigned)(a0.w & 1) << 24));
            v.y = to_pm1((unsigned)(a1.x & 1) | ((unsigned)(a1.y & 1) << 8) |
                         ((unsigned)(a1.z & 1) << 16) | ((unsigned)(a1.w & 1) << 24));
            v.z = to_pm1((unsigned)(a2.x & 1) | ((unsigned)(a2.y & 1) << 8) |
                         ((unsigned)(a2.z & 1) << 16) | ((unsigned)(a2.w & 1) << 24));
            v.w = to_pm1((unsigned)(a3.x & 1) | ((unsigned)(a3.y & 1) << 8) |
                         ((unsigned)(a3.z & 1) << 16) | ((unsigned)(a3.w & 1) << 24));
            *(uint4*)(x8p + ((size_t)p * 2048 + row) * 16) = v;   // coalesced
        }
    } else {
        const int bw = blockIdx.x - 256;           // 0..4095
        const int k0 = (bw & 63) * 64;
        const int n0 = (bw >> 6) * 64;

        // inline dtype detect (u8-bool vs int32): wave-reduce 1 KB prefix.
        const unsigned char* mb = (const unsigned char*)mraw;
        int myv = (mb[tid] != 0) + (mb[tid + 256] != 0) +
                  (mb[tid + 512] != 0) + (mb[tid + 768] != 0);
        #pragma unroll
        for (int d = 32; d; d >>= 1) myv += __shfl_xor(myv, d);
        const bool isU8 = (myv > 64);   // u8 ~128/wave, int32 ~32/wave

        // 4x4 byte micro-tile: rows k0+k4..+3, cols n0+n4..+3
        const int n4 = (tid & 15) * 4;
        const int k4 = (tid >> 4) * 4;
        unsigned int a[4];
        if (isU8) {
            #pragma unroll
            for (int r = 0; r < 4; ++r)
                a[r] = *(const unsigned int*)(mb + (size_t)(k0 + k4 + r) * DOUT + n0 + n4);
        } else {
            const int4* m32 = (const int4*)mraw;
            #pragma unroll
            for (int r = 0; r < 4; ++r) {
                int4 v = m32[((size_t)(k0 + k4 + r) * DOUT + n0 + n4) >> 2];
                a[r] = (unsigned int)(v.x & 1) |
                       ((unsigned int)(v.y & 1) << 8) |
                       ((unsigned int)(v.z & 1) << 16) |
                       ((unsigned int)(v.w & 1) << 24);
            }
        }
        // 4x4 byte transpose via v_perm (verified R7)
        unsigned int x0 = __builtin_amdgcn_perm(a[1], a[0], 0x05010400u);
        unsigned int x1 = __builtin_amdgcn_perm(a[3], a[2], 0x05010400u);
        unsigned int x2 = __builtin_amdgcn_perm(a[1], a[0], 0x07030602u);
        unsigned int x3 = __builtin_amdgcn_perm(a[3], a[2], 0x07030602u);
        unsigned int c0 = __builtin_amdgcn_perm(x1, x0, 0x05040100u);
        unsigned int c1 = __builtin_amdgcn_perm(x1, x0, 0x07060302u);
        unsigned int c2 = __builtin_amdgcn_perm(x3, x2, 0x05040100u);
        unsigned int c3 = __builtin_amdgcn_perm(x3, x2, 0x07060302u);
        // c_j = bytes k4..k4+3 of column o = n0+n4+j -> ±1, K-major store
        const int p   = (k0 + k4) >> 4;            // global panel
        const int off = k4 & 15;                   // byte offset in 16-B group
        *(unsigned int*)(b8p + ((size_t)p * 4096 + n0 + n4 + 0) * 16 + off) = to_pm1(c0);
        *(unsigned int*)(b8p + ((size_t)p * 4096 + n0 + n4 + 1) * 16 + off) = to_pm1(c1);
        *(unsigned int*)(b8p + ((size_t)p * 4096 + n0 + n4 + 2) * 16 + off) = to_pm1(c2);
        *(unsigned int*)(b8p + ((size_t)p * 4096 + n0 + n4 + 3) * 16 + off) = to_pm1(c3);
    }
}

// i8 MFMA GEMM: 128x128 block tile, 4 waves 2x2 (T=U=2 of 32x32x32_i8),
// BK=128 = 8 K-panels per chunk, 32 chunks, dbuf LDS 64 KB (2 blocks/CU),
// async global->LDS staging, K-major LDS (conflict-free frag reads).
__global__ __launch_bounds__(256)
void bgemm(const char* __restrict__ x8p,
           const char* __restrict__ b8p,
           const int* __restrict__ thr,
           int* __restrict__ out) {
    // XCD swizzle (verified R8): flat%8 = XCD, 8x8-block patch per XCD.
    const int flat = blockIdx.y * 32 + blockIdx.x;
    const int xcd  = flat & 7;
    const int idx  = flat >> 3;                    // 0..63
    const int bm   = (xcd & 1) * 8 + (idx & 7);    // 0..15
    const int bn   = (xcd >> 1) * 8 + (idx >> 3);  // 0..31
    const int m0   = bm * 128;
    const int o0   = bn * 128;

    const int tid  = threadIdx.x;
    const int lane = tid & 63;
    const int wv   = tid >> 6;           // wave 0..3
    const int wm   = (wv & 1) * 64;      // wave tile m origin
    const int wn   = (wv >> 1) * 64;     // wave tile n origin
    const int l31  = lane & 31;
    const int lh   = lane >> 5;

    __shared__ __align__(16) char lA[2][8 * 128 * 16];   // [panel][row][16B]
    __shared__ __align__(16) char lB[2][8 * 128 * 16];

    // stage chunk c (panels 8c..8c+7): wave wv stages panels 2wv, 2wv+1 of
    // both operands; per panel 2 instrs of 64 rows (contiguous 1 KB each).
    auto stage = [&](int c, int buf) {
        #pragma unroll
        for (int pp = 0; pp < 2; ++pp) {
            const int pl = 2 * wv + pp;            // local panel 0..7
            const int pg = 8 * c + pl;             // global panel
            #pragma unroll
            for (int h = 0; h < 2; ++h) {
                const int r = h * 64 + lane;
                async_load16(x8p + ((size_t)pg * 2048 + m0 + r) * 16,
                             &lA[buf][(pl * 128 + r) * 16]);
                async_load16(b8p + ((size_t)pg * 4096 + o0 + r) * 16,
                             &lB[buf][(pl * 128 + r) * 16]);
            }
        }
    };

    v16i acc[2][2];
    #pragma unroll
    for (int t = 0; t < 2; ++t)
        #pragma unroll
        for (int u = 0; u < 2; ++u)
            acc[t][u] = (v16i)(0);

    stage(0, 0);
    __syncthreads();

    for (int c = 0; c < 32; ++c) {
        const int buf = c & 1;
        if (c < 31) stage(c + 1, buf ^ 1);   // async, overlaps compute

        #pragma unroll
        for (int ks = 0; ks < 4; ++ks) {
            // MFMA ks consumes panels 2ks (lanes 0-31) / 2ks+1 (lanes 32-63):
            // lane l holds k = (l>>5)*16 + [0:16) of the 32-k step.
            const int poff = (2 * ks + lh) * 2048;
            v4i aF[2], bF[2];
            #pragma unroll
            for (int t = 0; t < 2; ++t) {
                aF[t] = *(const v4i*)&lA[buf][poff + (wm + t * 32 + l31) * 16];
                bF[t] = *(const v4i*)&lB[buf][poff + (wn + t * 32 + l31) * 16];
            }
            acc[0][0] = __builtin_amdgcn_mfma_i32_32x32x32_i8(aF[0], bF[0], acc[0][0], 0, 0, 0);
            acc[0][1] = __builtin_amdgcn_mfma_i32_32x32x32_i8(aF[0], bF[1], acc[0][1], 0, 0, 0);
            acc[1][0] = __builtin_amdgcn_mfma_i32_32x32x32_i8(aF[1], bF[0], acc[1][0], 0, 0, 0);
            acc[1][1] = __builtin_amdgcn_mfma_i32_32x32x32_i8(aF[1], bF[1], acc[1][1], 0, 0, 0);
        }
        __syncthreads();   // drains chunk+1 loads; releases buf
    }

    // epilogue: out = (dot± > 2*thr - 4096).
    // C/D layout (verified R7/R8): col = lane&31; row = (reg&3)+8*(reg>>2)+4*(lane>>5).
    #pragma unroll
    for (int u = 0; u < 2; ++u) {
        const int o   = o0 + wn + u * 32 + l31;
        const int lim = 2 * thr[o] - DIN;
        #pragma unroll
        for (int t = 0; t < 2; ++t) {
            #pragma unroll
            for (int r = 0; r < 16; ++r) {
                const int rowl = (r & 3) + 8 * (r >> 2) + 4 * lh;
                const int b    = m0 + wm + t * 32 + rowl;
                out[(size_t)b * DOUT + o] = (acc[t][u][r] > lim) ? 1 : 0;
            }
        }
    }
}

extern "C" void kernel_launch(void* const* d_in, const int* in_sizes, int n_in,
                              void* d_out, int out_size, void* d_ws, size_t ws_size,
                              hipStream_t stream) {
    const int* x          = (const int*)d_in[0];
    const void* masks     = d_in[1];           // bool: u8 or int32 (detected inline)
    const int* thresholds = (const int*)d_in[2];
    int* out              = (int*)d_out;

    char* x8p = (char*)d_ws;                          // 8 MB
    char* b8p = (char*)d_ws + ((size_t)8 << 20);      // 16 MB

    pack_all<<<256 + 4096, 256, 0, stream>>>(x, masks, x8p, b8p);
    bgemm<<<dim3(32, 16), 256, 0, stream>>>(x8p, b8p, thresholds, out);
}